// Round 5
// baseline (194.532 us; speedup 1.0000x reference)
//
#include <hip/hip_runtime.h>
#include <stdint.h>

#define KK 1000
#define NN 1000
#define MM 900000
#define FF 7
#define SENTINEL -9999.0f

// Constant-address-space cast: forces the backend to select s_load for the
// (uniform-base + constant-offset) weight reads. Generic-AS global loads are
// NEVER auto-scalarized (R1-R4 evidence: VGPR=32, VALUBusy 60%, identical
// codegen across 3 source restructurings). CK-proven idiom; c-style cast only.
#define AS4 __attribute__((address_space(4)))

// ---- macro repetition ------------------------------------------------------
#define R18(X) X(0) X(1) X(2) X(3) X(4) X(5) X(6) X(7) X(8) X(9) X(10) X(11) \
               X(12) X(13) X(14) X(15) X(16) X(17)
#define R36(X) R18(X) X(18) X(19) X(20) X(21) X(22) X(23) X(24) X(25) X(26) \
               X(27) X(28) X(29) X(30) X(31) X(32) X(33) X(34) X(35)

// ---------------- init: zero the packed grid (ws is poisoned 0xAA) ----------
__global__ __launch_bounds__(256) void init_grid(ulonglong2* __restrict__ g, int n2) {
    int i = blockIdx.x * 256 + threadIdx.x;
    if (i < n2) g[i] = make_ulonglong2(0ULL, 0ULL);
}

// ---------------- MLP + last-write-wins scatter -----------------------------
__global__ __launch_bounds__(256, 4) void mlp_scatter(
    const float* __restrict__ in,    // [F][M]
    const int*   __restrict__ idx,   // [2][M]
    const float* __restrict__ w1p, const float* __restrict__ b1p,   // 18x7, 18
    const float* __restrict__ w2p, const float* __restrict__ b2p,   // 36x18, 36
    const float* __restrict__ w3p, const float* __restrict__ b3p,   // 36x36, 36
    const float* __restrict__ w4p, const float* __restrict__ b4p,   // 1x36, 1
    unsigned long long* __restrict__ grid)                          // K*N packed
{
    const AS4 float* w1 = (const AS4 float*)w1p;
    const AS4 float* b1 = (const AS4 float*)b1p;
    const AS4 float* w2 = (const AS4 float*)w2p;
    const AS4 float* b2 = (const AS4 float*)b2p;
    const AS4 float* w3 = (const AS4 float*)w3p;
    const AS4 float* b3 = (const AS4 float*)b3p;
    const AS4 float* w4 = (const AS4 float*)w4p;
    const AS4 float* b4 = (const AS4 float*)b4p;

    int m0 = blockIdx.x * 256 + threadIdx.x;
    int m = m0 < MM ? m0 : (MM - 1);   // straight-line; tail lanes duplicate m=MM-1
                                       // and emit an identical packed atomic.

    float x0 = in[0 * MM + m], x1 = in[1 * MM + m], x2 = in[2 * MM + m],
          x3 = in[3 * MM + m], x4 = in[4 * MM + m], x5 = in[5 * MM + m],
          x6 = in[6 * MM + m];

#define L1(o) float h1_##o; { float a = b1[o];                                 \
    a = fmaf(w1[(o)*7+0], x0, a); a = fmaf(w1[(o)*7+1], x1, a);                \
    a = fmaf(w1[(o)*7+2], x2, a); a = fmaf(w1[(o)*7+3], x3, a);                \
    a = fmaf(w1[(o)*7+4], x4, a); a = fmaf(w1[(o)*7+5], x5, a);                \
    a = fmaf(w1[(o)*7+6], x6, a); h1_##o = fmaxf(a, 0.0f); }
    R18(L1)
#undef L1

#define L2(o) float h2_##o; { float a = b2[o];                                 \
    a = fmaf(w2[(o)*18+ 0], h1_0,  a); a = fmaf(w2[(o)*18+ 1], h1_1,  a);      \
    a = fmaf(w2[(o)*18+ 2], h1_2,  a); a = fmaf(w2[(o)*18+ 3], h1_3,  a);      \
    a = fmaf(w2[(o)*18+ 4], h1_4,  a); a = fmaf(w2[(o)*18+ 5], h1_5,  a);      \
    a = fmaf(w2[(o)*18+ 6], h1_6,  a); a = fmaf(w2[(o)*18+ 7], h1_7,  a);      \
    a = fmaf(w2[(o)*18+ 8], h1_8,  a); a = fmaf(w2[(o)*18+ 9], h1_9,  a);      \
    a = fmaf(w2[(o)*18+10], h1_10, a); a = fmaf(w2[(o)*18+11], h1_11, a);      \
    a = fmaf(w2[(o)*18+12], h1_12, a); a = fmaf(w2[(o)*18+13], h1_13, a);      \
    a = fmaf(w2[(o)*18+14], h1_14, a); a = fmaf(w2[(o)*18+15], h1_15, a);      \
    a = fmaf(w2[(o)*18+16], h1_16, a); a = fmaf(w2[(o)*18+17], h1_17, a);      \
    h2_##o = fmaxf(a, 0.0f); }
    R36(L2)
#undef L2

    // Layer 3 fused with layer 4: h3 never materializes.
    float v = b4[0];
#define L34(o) { float a = b3[o];                                              \
    a = fmaf(w3[(o)*36+ 0], h2_0,  a); a = fmaf(w3[(o)*36+ 1], h2_1,  a);      \
    a = fmaf(w3[(o)*36+ 2], h2_2,  a); a = fmaf(w3[(o)*36+ 3], h2_3,  a);      \
    a = fmaf(w3[(o)*36+ 4], h2_4,  a); a = fmaf(w3[(o)*36+ 5], h2_5,  a);      \
    a = fmaf(w3[(o)*36+ 6], h2_6,  a); a = fmaf(w3[(o)*36+ 7], h2_7,  a);      \
    a = fmaf(w3[(o)*36+ 8], h2_8,  a); a = fmaf(w3[(o)*36+ 9], h2_9,  a);      \
    a = fmaf(w3[(o)*36+10], h2_10, a); a = fmaf(w3[(o)*36+11], h2_11, a);      \
    a = fmaf(w3[(o)*36+12], h2_12, a); a = fmaf(w3[(o)*36+13], h2_13, a);      \
    a = fmaf(w3[(o)*36+14], h2_14, a); a = fmaf(w3[(o)*36+15], h2_15, a);      \
    a = fmaf(w3[(o)*36+16], h2_16, a); a = fmaf(w3[(o)*36+17], h2_17, a);      \
    a = fmaf(w3[(o)*36+18], h2_18, a); a = fmaf(w3[(o)*36+19], h2_19, a);      \
    a = fmaf(w3[(o)*36+20], h2_20, a); a = fmaf(w3[(o)*36+21], h2_21, a);      \
    a = fmaf(w3[(o)*36+22], h2_22, a); a = fmaf(w3[(o)*36+23], h2_23, a);      \
    a = fmaf(w3[(o)*36+24], h2_24, a); a = fmaf(w3[(o)*36+25], h2_25, a);      \
    a = fmaf(w3[(o)*36+26], h2_26, a); a = fmaf(w3[(o)*36+27], h2_27, a);      \
    a = fmaf(w3[(o)*36+28], h2_28, a); a = fmaf(w3[(o)*36+29], h2_29, a);      \
    a = fmaf(w3[(o)*36+30], h2_30, a); a = fmaf(w3[(o)*36+31], h2_31, a);      \
    a = fmaf(w3[(o)*36+32], h2_32, a); a = fmaf(w3[(o)*36+33], h2_33, a);      \
    a = fmaf(w3[(o)*36+34], h2_34, a); a = fmaf(w3[(o)*36+35], h2_35, a);      \
    v = fmaf(w4[o], fmaxf(a, 0.0f), v); }
    R36(L34)
#undef L34

    int r = idx[m];
    int c = idx[MM + m];
    // high word = m+1 (unique, later m wins => numpy last-write-wins),
    // low word = value bits (payload only, never decides the compare)
    unsigned long long packed =
        ((unsigned long long)(unsigned)(m + 1) << 32) | (unsigned)__float_as_uint(v);
    atomicMax(&grid[r * NN + c], packed);
}

// ---------------- fused reduction: row maxes + column partials --------------
#define RPB     10              // rows per block -> 100 blocks
#define NBLK    (KK / RPB)      // 100

__global__ __launch_bounds__(256) void reduce_grid(const unsigned long long* __restrict__ g,
                                                   float* __restrict__ out,   // row max -> out[0..K)
                                                   float* __restrict__ part)  // col partials [NBLK][NN]
{
    int tid = threadIdx.x;
    int r0  = blockIdx.x * RPB;
    float cmax0 = SENTINEL, cmax1 = SENTINEL, cmax2 = SENTINEL, cmax3 = SENTINEL;
    __shared__ float red[4];

    for (int rr = 0; rr < RPB; ++rr) {
        int r = r0 + rr;
        const unsigned long long* row = g + (size_t)r * NN;
        float rmax = SENTINEL;
        {
            unsigned long long p = row[tid];
            if (p) { float val = __uint_as_float((unsigned)p); rmax = fmaxf(rmax, val); cmax0 = fmaxf(cmax0, val); }
        }
        {
            unsigned long long p = row[tid + 256];
            if (p) { float val = __uint_as_float((unsigned)p); rmax = fmaxf(rmax, val); cmax1 = fmaxf(cmax1, val); }
        }
        {
            unsigned long long p = row[tid + 512];
            if (p) { float val = __uint_as_float((unsigned)p); rmax = fmaxf(rmax, val); cmax2 = fmaxf(cmax2, val); }
        }
        if (tid < NN - 768) {
            unsigned long long p = row[tid + 768];
            if (p) { float val = __uint_as_float((unsigned)p); rmax = fmaxf(rmax, val); cmax3 = fmaxf(cmax3, val); }
        }
        // wave-level reduce, then 4-wave LDS combine
        for (int s = 32; s > 0; s >>= 1) rmax = fmaxf(rmax, __shfl_down(rmax, s, 64));
        if ((tid & 63) == 0) red[tid >> 6] = rmax;
        __syncthreads();
        if (tid == 0) out[r] = fmaxf(fmaxf(red[0], red[1]), fmaxf(red[2], red[3]));
        __syncthreads();
    }

    float* p = part + (size_t)blockIdx.x * NN;
    p[tid]       = cmax0;
    p[tid + 256] = cmax1;
    p[tid + 512] = cmax2;
    if (tid < NN - 768) p[tid + 768] = cmax3;
}

__global__ __launch_bounds__(256) void col_final(const float* __restrict__ part,
                                                 float* __restrict__ out) {
    int n = blockIdx.x * 256 + threadIdx.x;
    if (n >= NN) return;
    float mx = SENTINEL;
    for (int c = 0; c < NBLK; ++c) mx = fmaxf(mx, part[c * NN + n]);
    out[KK + n] = mx;
}

extern "C" void kernel_launch(void* const* d_in, const int* in_sizes, int n_in,
                              void* d_out, int out_size, void* d_ws, size_t ws_size,
                              hipStream_t stream) {
    const float* in  = (const float*)d_in[0];
    // d_in[1] = T_out (zeros) — unused
    const int*   idx = (const int*)d_in[2];
    const float* w1  = (const float*)d_in[3];
    const float* b1  = (const float*)d_in[4];
    const float* w2  = (const float*)d_in[5];
    const float* b2  = (const float*)d_in[6];
    const float* w3  = (const float*)d_in[7];
    const float* b3  = (const float*)d_in[8];
    const float* w4  = (const float*)d_in[9];
    const float* b4  = (const float*)d_in[10];

    unsigned long long* grid = (unsigned long long*)d_ws;            // 8 MB
    float* part = (float*)((char*)d_ws + (size_t)KK * NN * 8);       // 400 KB
    float* out  = (float*)d_out;

    const int n2 = (KK * NN) / 2;  // ulonglong2 elements
    init_grid<<<(n2 + 255) / 256, 256, 0, stream>>>((ulonglong2*)grid, n2);

    mlp_scatter<<<(MM + 255) / 256, 256, 0, stream>>>(
        in, idx, w1, b1, w2, b2, w3, b3, w4, b4, grid);

    reduce_grid<<<NBLK, 256, 0, stream>>>(grid, out, part);
    col_final<<<4, 256, 0, stream>>>(part, out);
}

// Round 6
// 175.286 us; speedup vs baseline: 1.1098x; 1.1098x over previous
//
#include <hip/hip_runtime.h>
#include <stdint.h>

#define KK 1000
#define NN 1000
#define MM 900000
#define HALF 450000
#define FF 7
#define SENTINEL -9999.0f

// ---- macro repetition ------------------------------------------------------
#define R18(X) X(0) X(1) X(2) X(3) X(4) X(5) X(6) X(7) X(8) X(9) X(10) X(11) \
               X(12) X(13) X(14) X(15) X(16) X(17)
#define R36(X) R18(X) X(18) X(19) X(20) X(21) X(22) X(23) X(24) X(25) X(26) \
               X(27) X(28) X(29) X(30) X(31) X(32) X(33) X(34) X(35)

// ---- LDS weight layout (floats) -------------------------------------------
#define OW1 0
#define OB1 126
#define OW2 144
#define OB2 792
#define OW3 828
#define OB3 2124
#define OW4 2160
#define OB4 2196
#define WTOT 2197

// ---------------- init: zero the packed grid (ws is poisoned 0xAA) ----------
__global__ __launch_bounds__(256) void init_grid(ulonglong2* __restrict__ g, int n2) {
    int i = blockIdx.x * 256 + threadIdx.x;
    if (i < n2) g[i] = make_ulonglong2(0ULL, 0ULL);
}

// ---------------- MLP + last-write-wins scatter -----------------------------
// R1-R5: per-FMA global weight loads -> VMEM-bound streaming schedule
// (VGPR=32, VALUBusy 60%, 86us) immune to all source hints. Structural fix:
// weights staged in LDS once per block (broadcast ds_read, conflict-free),
// 2 points per thread so each weight read feeds 2 FMAs, named scalars.
__global__ __launch_bounds__(256, 2) void mlp_scatter(
    const float* __restrict__ in,    // [F][M]
    const int*   __restrict__ idx,   // [2][M]
    const float* __restrict__ w1, const float* __restrict__ b1,   // 18x7, 18
    const float* __restrict__ w2, const float* __restrict__ b2,   // 36x18, 36
    const float* __restrict__ w3, const float* __restrict__ b3,   // 36x36, 36
    const float* __restrict__ w4, const float* __restrict__ b4,   // 1x36, 1
    unsigned long long* __restrict__ grid)                        // K*N packed
{
    __shared__ float W[WTOT];
    int tid = threadIdx.x;
    for (int i = tid; i < 126;  i += 256) W[OW1 + i] = w1[i];
    for (int i = tid; i < 18;   i += 256) W[OB1 + i] = b1[i];
    for (int i = tid; i < 648;  i += 256) W[OW2 + i] = w2[i];
    for (int i = tid; i < 36;   i += 256) W[OB2 + i] = b2[i];
    for (int i = tid; i < 1296; i += 256) W[OW3 + i] = w3[i];
    for (int i = tid; i < 36;   i += 256) W[OB3 + i] = b3[i];
    for (int i = tid; i < 36;   i += 256) W[OW4 + i] = w4[i];
    if (tid == 0) W[OB4] = b4[0];
    __syncthreads();

    int t = blockIdx.x * 256 + tid;
    if (t >= HALF) t = HALF - 1;   // tail lanes duplicate t=HALF-1: identical
    int mA = t, mB = t + HALF;     // packed atomics, idempotent.

    float x0_0 = in[0*MM+mA], x0_1 = in[0*MM+mB];
    float x1_0 = in[1*MM+mA], x1_1 = in[1*MM+mB];
    float x2_0 = in[2*MM+mA], x2_1 = in[2*MM+mB];
    float x3_0 = in[3*MM+mA], x3_1 = in[3*MM+mB];
    float x4_0 = in[4*MM+mA], x4_1 = in[4*MM+mB];
    float x5_0 = in[5*MM+mA], x5_1 = in[5*MM+mB];
    float x6_0 = in[6*MM+mA], x6_1 = in[6*MM+mB];

#define L1(o) float h1_##o##_0, h1_##o##_1; { \
    float a0 = W[OB1+(o)], a1 = a0, w; \
    w=W[OW1+(o)*7+0]; a0=fmaf(w,x0_0,a0); a1=fmaf(w,x0_1,a1); \
    w=W[OW1+(o)*7+1]; a0=fmaf(w,x1_0,a0); a1=fmaf(w,x1_1,a1); \
    w=W[OW1+(o)*7+2]; a0=fmaf(w,x2_0,a0); a1=fmaf(w,x2_1,a1); \
    w=W[OW1+(o)*7+3]; a0=fmaf(w,x3_0,a0); a1=fmaf(w,x3_1,a1); \
    w=W[OW1+(o)*7+4]; a0=fmaf(w,x4_0,a0); a1=fmaf(w,x4_1,a1); \
    w=W[OW1+(o)*7+5]; a0=fmaf(w,x5_0,a0); a1=fmaf(w,x5_1,a1); \
    w=W[OW1+(o)*7+6]; a0=fmaf(w,x6_0,a0); a1=fmaf(w,x6_1,a1); \
    h1_##o##_0=fmaxf(a0,0.0f); h1_##o##_1=fmaxf(a1,0.0f); }
    R18(L1)
#undef L1

#define T2(o,i) w=W[OW2+(o)*18+(i)]; a0=fmaf(w,h1_##i##_0,a0); a1=fmaf(w,h1_##i##_1,a1);
#define L2(o) float h2_##o##_0, h2_##o##_1; { \
    float a0 = W[OB2+(o)], a1 = a0, w; \
    T2(o,0) T2(o,1) T2(o,2) T2(o,3) T2(o,4) T2(o,5) T2(o,6) T2(o,7) T2(o,8) \
    T2(o,9) T2(o,10) T2(o,11) T2(o,12) T2(o,13) T2(o,14) T2(o,15) T2(o,16) T2(o,17) \
    h2_##o##_0=fmaxf(a0,0.0f); h2_##o##_1=fmaxf(a1,0.0f); }
    R36(L2)
#undef L2
#undef T2

    float v0 = W[OB4], v1 = v0;
#define T3(o,i) w=W[OW3+(o)*36+(i)]; a0=fmaf(w,h2_##i##_0,a0); a1=fmaf(w,h2_##i##_1,a1);
#define L34(o) { float a0 = W[OB3+(o)], a1 = a0, w; \
    T3(o,0)  T3(o,1)  T3(o,2)  T3(o,3)  T3(o,4)  T3(o,5)  T3(o,6)  T3(o,7)  \
    T3(o,8)  T3(o,9)  T3(o,10) T3(o,11) T3(o,12) T3(o,13) T3(o,14) T3(o,15) \
    T3(o,16) T3(o,17) T3(o,18) T3(o,19) T3(o,20) T3(o,21) T3(o,22) T3(o,23) \
    T3(o,24) T3(o,25) T3(o,26) T3(o,27) T3(o,28) T3(o,29) T3(o,30) T3(o,31) \
    T3(o,32) T3(o,33) T3(o,34) T3(o,35) \
    w = W[OW4+(o)]; \
    v0 = fmaf(w, fmaxf(a0,0.0f), v0); v1 = fmaf(w, fmaxf(a1,0.0f), v1); }
    R36(L34)
#undef L34
#undef T3

    int rA = idx[mA], cA = idx[MM + mA];
    int rB = idx[mB], cB = idx[MM + mB];
    // high word = m+1 (unique, later m wins => numpy last-write-wins),
    // low word = value bits (payload only, never decides the compare)
    unsigned long long pA =
        ((unsigned long long)(unsigned)(mA + 1) << 32) | (unsigned)__float_as_uint(v0);
    unsigned long long pB =
        ((unsigned long long)(unsigned)(mB + 1) << 32) | (unsigned)__float_as_uint(v1);
    atomicMax(&grid[rA * NN + cA], pA);
    atomicMax(&grid[rB * NN + cB], pB);
}

// ---------------- row max: one block per row, single barrier ----------------
__global__ __launch_bounds__(256) void row_max_k(const unsigned long long* __restrict__ g,
                                                 float* __restrict__ out) {
    int r = blockIdx.x;
    float mx = SENTINEL;
    for (int c = threadIdx.x; c < NN; c += 256) {
        unsigned long long p = g[(size_t)r * NN + c];
        if (p) mx = fmaxf(mx, __uint_as_float((unsigned)p));
    }
    for (int s = 32; s > 0; s >>= 1) mx = fmaxf(mx, __shfl_down(mx, s, 64));
    __shared__ float red[4];
    if ((threadIdx.x & 63) == 0) red[threadIdx.x >> 6] = mx;
    __syncthreads();
    if (threadIdx.x == 0) out[r] = fmaxf(fmaxf(red[0], red[1]), fmaxf(red[2], red[3]));
}

// ---------------- col max: partials over row-chunks, then final -------------
#define CCHUNKS 25
#define CROWS   (KK / CCHUNKS)   // 40

__global__ __launch_bounds__(256) void col_partial(const unsigned long long* __restrict__ g,
                                                   float* __restrict__ part) {
    int n = blockIdx.x * 256 + threadIdx.x;
    if (n >= NN) return;
    int k0 = blockIdx.y * CROWS;
    float mx = SENTINEL;
    for (int k = k0; k < k0 + CROWS; ++k) {
        unsigned long long p = g[(size_t)k * NN + n];
        if (p) mx = fmaxf(mx, __uint_as_float((unsigned)p));
    }
    part[blockIdx.y * NN + n] = mx;
}

__global__ __launch_bounds__(256) void col_final(const float* __restrict__ part,
                                                 float* __restrict__ out) {
    int n = blockIdx.x * 256 + threadIdx.x;
    if (n >= NN) return;
    float mx = SENTINEL;
#pragma unroll
    for (int c = 0; c < CCHUNKS; ++c) mx = fmaxf(mx, part[c * NN + n]);
    out[KK + n] = mx;
}

extern "C" void kernel_launch(void* const* d_in, const int* in_sizes, int n_in,
                              void* d_out, int out_size, void* d_ws, size_t ws_size,
                              hipStream_t stream) {
    const float* in  = (const float*)d_in[0];
    // d_in[1] = T_out (zeros) — unused
    const int*   idx = (const int*)d_in[2];
    const float* w1  = (const float*)d_in[3];
    const float* b1  = (const float*)d_in[4];
    const float* w2  = (const float*)d_in[5];
    const float* b2  = (const float*)d_in[6];
    const float* w3  = (const float*)d_in[7];
    const float* b3  = (const float*)d_in[8];
    const float* w4  = (const float*)d_in[9];
    const float* b4  = (const float*)d_in[10];

    unsigned long long* grid = (unsigned long long*)d_ws;            // 8 MB
    float* part = (float*)((char*)d_ws + (size_t)KK * NN * 8);       // 100 KB
    float* out  = (float*)d_out;

    const int n2 = (KK * NN) / 2;  // ulonglong2 elements
    init_grid<<<(n2 + 255) / 256, 256, 0, stream>>>((ulonglong2*)grid, n2);

    mlp_scatter<<<(HALF + 255) / 256, 256, 0, stream>>>(
        in, idx, w1, b1, w2, b2, w3, b3, w4, b4, grid);

    row_max_k<<<KK, 256, 0, stream>>>(grid, out);
    col_partial<<<dim3(4, CCHUNKS), 256, 0, stream>>>(grid, part);
    col_final<<<4, 256, 0, stream>>>(part, out);
}